// Round 7
// baseline (494.579 us; speedup 1.0000x reference)
//
#include <hip/hip_runtime.h>
#include <math.h>

#define BB_   2
#define CIN_  256
#define NTOK_ 2048
#define FF_   512
#define COUT_ 256
#define NH_   8
#define DH_   64
#define HW_   128
#define BNEPS_ 1e-5f
#define SCALE_LOG2_ 0.09016844005556021f  /* log2(e)/16, folded into K at qkv */

// Diagnostic repeat factors: inflate each kernel past the 42 us fill so its
// dispatch (with counters) surfaces in rocprof top-5. Per-rep cost = dur/REP.
#define PREP_REP_ 16
#define QKV_REP_  8
#define ATTN_REP_ 8
#define PROJ_REP_ 8
#define BN_REP_   16

typedef __attribute__((ext_vector_type(8))) short short8;
typedef __attribute__((ext_vector_type(4))) short bfx4;
typedef __attribute__((ext_vector_type(4))) float f32x4;

#if __has_builtin(__builtin_amdgcn_mfma_f32_16x16x16_bf16)
#define MFMA16(a, b, c) __builtin_amdgcn_mfma_f32_16x16x16_bf16(a, b, c, 0, 0, 0)
#else
#define MFMA16(a, b, c) __builtin_amdgcn_mfma_f32_16x16x16bf16_1k(a, b, c, 0, 0, 0)
#endif

__device__ inline unsigned short f2bf(float f) {
  union { float f; unsigned u; } v; v.f = f;
  unsigned r = (v.u + 0x7FFF + ((v.u >> 16) & 1)) >> 16;  // RNE
  return (unsigned short)r;
}

// async global->LDS DMA, 16 B per lane; LDS dest = wave-uniform base + lane*16
__device__ __forceinline__ void dma16(const unsigned short* g, unsigned short* l) {
  __builtin_amdgcn_global_load_lds(
      (const __attribute__((address_space(1))) void*)g,
      (__attribute__((address_space(3))) void*)l, 16, 0, 0);
}

// ---------------------------------------------------------------------------
// Kernel 0: prep — x fp32 [b][c][n] -> xT bf16 [b][n][c]; weights -> bf16.
// ---------------------------------------------------------------------------
__global__ __launch_bounds__(256) void prep_kernel(
    const float* __restrict__ x, const float* __restrict__ WK,
    const float* __restrict__ WQ, const float* __restrict__ WV,
    const float* __restrict__ Wo, unsigned short* __restrict__ xT,
    unsigned short* __restrict__ Wkb, unsigned short* __restrict__ Wqb,
    unsigned short* __restrict__ Wvb, unsigned short* __restrict__ Wob) {
  __shared__ float T[64 * 65];
  const int tid = threadIdx.x;
  const int bid = blockIdx.x;
  for (int rep = 0; rep < PREP_REP_; ++rep) {
    if (bid < 256) {
      const int b = bid >> 7;
      const int rem = bid & 127;
      const int n0 = (rem >> 2) * 64;
      const int c0 = (rem & 3) * 64;
#pragma unroll
      for (int p = 0; p < 4; ++p) {
        const int idx = tid + 256 * p;
        const int row = idx >> 4, col = (idx & 15) * 4;
        const float4 v =
            *(const float4*)(x + (size_t)(b * CIN_ + c0 + row) * NTOK_ + n0 + col);
        T[row * 65 + col + 0] = v.x; T[row * 65 + col + 1] = v.y;
        T[row * 65 + col + 2] = v.z; T[row * 65 + col + 3] = v.w;
      }
      __syncthreads();
#pragma unroll
      for (int p = 0; p < 2; ++p) {
        const int idx = tid + 256 * p;
        const int nl = idx >> 3, c8 = (idx & 7) * 8;
        unsigned short u[8];
#pragma unroll
        for (int i = 0; i < 8; ++i) u[i] = f2bf(T[(c8 + i) * 65 + nl]);
        *(uint4*)(xT + ((size_t)(b * NTOK_ + n0 + nl)) * CIN_ + c0 + c8) =
            *(uint4*)u;
      }
    } else {
      const int t = bid - 256;
      const int which = t >> 5, blk = t & 31;
      const float* src = which == 0 ? WK : which == 1 ? WQ : which == 2 ? WV : Wo;
      unsigned short* dst = which == 0 ? Wkb : which == 1 ? Wqb : which == 2 ? Wvb : Wob;
      const int base = blk * 4096 + tid * 16;
#pragma unroll
      for (int p = 0; p < 4; ++p) {
        const float4 v = *(const float4*)(src + base + p * 4);
        ushort4 u;
        u.x = f2bf(v.x); u.y = f2bf(v.y); u.z = f2bf(v.z); u.w = f2bf(v.w);
        *(ushort4*)(dst + base + p * 4) = u;
      }
    }
    __syncthreads();                 // LDS reuse guard across reps
    asm volatile("" ::: "memory");   // block cross-rep DSE/CSE
  }
}

// ---------------------------------------------------------------------------
// Kernel 1: QKV projection via MFMA. 128f x 64n tile, 768 blocks, 3 blocks/CU.
// ---------------------------------------------------------------------------
__global__ __launch_bounds__(256, 3) void qkv_kernel(
    const unsigned short* __restrict__ xT, const unsigned short* __restrict__ Wkb,
    const unsigned short* __restrict__ Wqb, const unsigned short* __restrict__ Wvb,
    unsigned short* __restrict__ Kb, unsigned short* __restrict__ Qb,
    unsigned short* __restrict__ Vt) {
  __shared__ unsigned short Wsh[128 * 72];
  __shared__ unsigned short Xsh[64 * 72];
  const int tid = threadIdx.x;
  const int lane = tid & 63, w = tid >> 6;
  const int lx = lane & 15, q = lane >> 4;
  const int wm = w >> 1, wn = w & 1;
  const int n0 = blockIdx.x * 64;
  const int f0 = blockIdx.y * 128;
  const int b = blockIdx.z / 3, which = blockIdx.z % 3;
  const unsigned short* Wb = which == 0 ? Wkb : which == 1 ? Wqb : Wvb;

  const int srow = tid >> 3;
  const int soff = (tid & 7) * 8;
  const unsigned short* Wg = Wb + (size_t)(f0 + srow) * CIN_ + soff;
  const unsigned short* Xg = xT + ((size_t)(b * NTOK_ + n0 + srow)) * CIN_ + soff;

  for (int rep = 0; rep < QKV_REP_; ++rep) {
    uint4 wr[4], xr[2];
#pragma unroll
    for (int r = 0; r < 4; ++r) wr[r] = *(const uint4*)(Wg + (size_t)(32 * r) * CIN_);
#pragma unroll
    for (int r = 0; r < 2; ++r) xr[r] = *(const uint4*)(Xg + (size_t)(32 * r) * CIN_);

    f32x4 acc[4][2];
#pragma unroll
    for (int i = 0; i < 4; ++i)
#pragma unroll
      for (int j = 0; j < 2; ++j) acc[i][j] = (f32x4){0.f, 0.f, 0.f, 0.f};

    for (int kk = 0; kk < 4; ++kk) {
      __syncthreads();
#pragma unroll
      for (int r = 0; r < 4; ++r) *(uint4*)(Wsh + (srow + 32 * r) * 72 + soff) = wr[r];
#pragma unroll
      for (int r = 0; r < 2; ++r) *(uint4*)(Xsh + (srow + 32 * r) * 72 + soff) = xr[r];
      if (kk < 3) {
        const int c0 = (kk + 1) * 64;
#pragma unroll
        for (int r = 0; r < 4; ++r) wr[r] = *(const uint4*)(Wg + (size_t)(32 * r) * CIN_ + c0);
#pragma unroll
        for (int r = 0; r < 2; ++r) xr[r] = *(const uint4*)(Xg + (size_t)(32 * r) * CIN_ + c0);
      }
      __syncthreads();
      short8 xF[2][2];
#pragma unroll
      for (int i = 0; i < 2; ++i) {
        xF[i][0] = *(const short8*)(Xsh + (32 * wn + 16 * i + lx) * 72 + q * 8);
        xF[i][1] = *(const short8*)(Xsh + (32 * wn + 16 * i + lx) * 72 + 32 + q * 8);
      }
      if (which < 2) {
#pragma unroll
        for (int i = 0; i < 4; ++i) {
          const short8 w0 = *(const short8*)(Wsh + (64 * wm + 16 * i + lx) * 72 + q * 8);
          const short8 w1 = *(const short8*)(Wsh + (64 * wm + 16 * i + lx) * 72 + 32 + q * 8);
#pragma unroll
          for (int j = 0; j < 2; ++j) {
            acc[i][j] = __builtin_amdgcn_mfma_f32_16x16x32_bf16(w0, xF[j][0], acc[i][j], 0, 0, 0);
            acc[i][j] = __builtin_amdgcn_mfma_f32_16x16x32_bf16(w1, xF[j][1], acc[i][j], 0, 0, 0);
          }
        }
      } else {
#pragma unroll
        for (int jf = 0; jf < 4; ++jf) {
          const short8 w0 = *(const short8*)(Wsh + (64 * wm + 16 * jf + lx) * 72 + q * 8);
          const short8 w1 = *(const short8*)(Wsh + (64 * wm + 16 * jf + lx) * 72 + 32 + q * 8);
#pragma unroll
          for (int i = 0; i < 2; ++i) {
            acc[jf][i] = __builtin_amdgcn_mfma_f32_16x16x32_bf16(xF[i][0], w0, acc[jf][i], 0, 0, 0);
            acc[jf][i] = __builtin_amdgcn_mfma_f32_16x16x32_bf16(xF[i][1], w1, acc[jf][i], 0, 0, 0);
          }
        }
      }
    }

    const int h = (f0 >> 6) + wm;
    if (which < 2) {
      unsigned short* Y = (which == 0 ? Kb : Qb);
      const float sc = (which == 0) ? SCALE_LOG2_ : 1.0f;
#pragma unroll
      for (int i = 0; i < 4; ++i)
#pragma unroll
        for (int j = 0; j < 2; ++j) {
          const int n = n0 + 32 * wn + 16 * j + lx;
          const int d0 = 16 * i + 4 * q;
          ushort4 u;
          u.x = f2bf(acc[i][j][0] * sc); u.y = f2bf(acc[i][j][1] * sc);
          u.z = f2bf(acc[i][j][2] * sc); u.w = f2bf(acc[i][j][3] * sc);
          *(ushort4*)(Y + ((size_t)((b * NH_ + h) * NTOK_ + n)) * DH_ + d0) = u;
        }
    } else {
#pragma unroll
      for (int jf = 0; jf < 4; ++jf)
#pragma unroll
        for (int i = 0; i < 2; ++i) {
          const int d = 16 * jf + lx;
          const int n = n0 + 32 * wn + 16 * i + 4 * q;
          ushort4 u;
          u.x = f2bf(acc[jf][i][0]); u.y = f2bf(acc[jf][i][1]);
          u.z = f2bf(acc[jf][i][2]); u.w = f2bf(acc[jf][i][3]);
          *(ushort4*)(Vt + ((size_t)((b * NH_ + h) * DH_ + d)) * NTOK_ + n) = u;
        }
    }
    asm volatile("" ::: "memory");
  }
}

// ---------------------------------------------------------------------------
// Kernel 2: block-causal attention (S^T trick, DMA dbuf, XCD grouping, LPT).
// ---------------------------------------------------------------------------
__global__ __launch_bounds__(256, 2) void attn_kernel(
    const unsigned short* __restrict__ Kb, const unsigned short* __restrict__ Qb,
    const unsigned short* __restrict__ Vt, unsigned short* __restrict__ Ob) {
  __shared__ __align__(16) unsigned short Qbuf[2][8192];
  __shared__ __align__(16) unsigned short Vbuf[2][8192];

  const int tid = threadIdx.x;
  const int lane = tid & 63;
  const int w = tid >> 6;
  const int lx = lane & 15;
  const int g = lane >> 4;

  const int bid = blockIdx.x;
  const int xcd = bid & 7;
  const int k = bid >> 3;
  const int bh = xcd * 2 + (k & 1);
  const int u = k >> 1;
  const int iblk = (u < 16) ? (31 - u) : (u - 16);
  const int h = bh & 7, b = bh >> 3;
  const int i0 = iblk * 64;
  const int njt = (iblk >> 1) + 1;

  const size_t bhs = (size_t)b * NH_ + h;
  const unsigned short* Kg = Kb + bhs * (size_t)NTOK_ * DH_ + (size_t)i0 * DH_;
  const unsigned short* Qg = Qb + bhs * (size_t)NTOK_ * DH_;
  const unsigned short* Vg = Vt + bhs * (size_t)DH_ * NTOK_;

  auto stage = [&](int buf, int j0) {
#pragma unroll
    for (int cc = 0; cc < 4; ++cc) {
      const int chunk = 4 * w + cc;
      {  // Q
        const int row = chunk * 8 + (lane >> 3);
        const int grp = (lane & 7) ^ (row & 7);
        dma16(Qg + (size_t)(j0 + row) * DH_ + grp * 8, &Qbuf[buf][chunk * 512]);
      }
      {  // V
        const int row = chunk * 4 + (lane >> 4);
        const int grp = (lane & 15) ^ (row & 7);
        dma16(Vg + (size_t)row * NTOK_ + j0 + grp * 8, &Vbuf[buf][chunk * 512]);
      }
    }
  };

  const int fr0 = ((g ^ (lx & 7)) << 3);
  const int fr1 = (((4 + g) ^ (lx & 7)) << 3);

  for (int rep = 0; rep < ATTN_REP_; ++rep) {
    const short8 aK0 = *(const short8*)(Kg + (16 * w + lx) * DH_ + g * 8);
    const short8 aK1 = *(const short8*)(Kg + (16 * w + lx) * DH_ + 32 + g * 8);

    f32x4 o[4];
#pragma unroll
    for (int t = 0; t < 4; ++t) o[t] = (f32x4){0.f, 0.f, 0.f, 0.f};
    float rs = 0.f;

    stage(0, 0);
    __syncthreads();

    int cur = 0;
    for (int jt = 0; jt < njt; ++jt) {
      if (jt + 1 < njt) stage(cur ^ 1, (jt + 1) * 128);

      const unsigned short* Qs = Qbuf[cur];
      const unsigned short* Vs = Vbuf[cur];

      f32x4 sa[8];
#pragma unroll
      for (int s = 0; s < 8; ++s) {
        const int row = 16 * s + lx;
        const short8 a0 = *(const short8*)(Qs + row * 64 + fr0);
        const short8 a1 = *(const short8*)(Qs + row * 64 + fr1);
        sa[s] = (f32x4){0.f, 0.f, 0.f, 0.f};
        sa[s] = __builtin_amdgcn_mfma_f32_16x16x32_bf16(a0, aK0, sa[s], 0, 0, 0);
        sa[s] = __builtin_amdgcn_mfma_f32_16x16x32_bf16(a1, aK1, sa[s], 0, 0, 0);
      }

#pragma unroll
      for (int s = 0; s < 8; ++s) {
        const float p0 = __builtin_amdgcn_exp2f(sa[s][0]);
        const float p1 = __builtin_amdgcn_exp2f(sa[s][1]);
        const float p2 = __builtin_amdgcn_exp2f(sa[s][2]);
        const float p3 = __builtin_amdgcn_exp2f(sa[s][3]);
        rs += (p0 + p1) + (p2 + p3);
        union { unsigned u[2]; bfx4 v; } pk;
        pk.u[0] = (__builtin_bit_cast(unsigned, p0) >> 16) |
                  (__builtin_bit_cast(unsigned, p1) & 0xFFFF0000u);
        pk.u[1] = (__builtin_bit_cast(unsigned, p2) >> 16) |
                  (__builtin_bit_cast(unsigned, p3) & 0xFFFF0000u);
        const int jgrp = 2 * s + (g >> 1);
        const int joff = (g & 1) << 2;
#pragma unroll
        for (int t = 0; t < 4; ++t) {
          const int row = 16 * t + lx;
          const bfx4 va = *(const bfx4*)(Vs + row * 128 +
                                         ((jgrp ^ (row & 7)) << 3) + joff);
          o[t] = MFMA16(va, pk.v, o[t]);
        }
      }

      __syncthreads();
      cur ^= 1;
    }

    rs += __shfl_xor(rs, 16);
    rs += __shfl_xor(rs, 32);
    const float invl = 1.0f / rs;
    const int n = i0 + 16 * w + lx;
#pragma unroll
    for (int t = 0; t < 4; ++t) {
      ushort4 uo;
      uo.x = f2bf(o[t][0] * invl); uo.y = f2bf(o[t][1] * invl);
      uo.z = f2bf(o[t][2] * invl); uo.w = f2bf(o[t][3] * invl);
      *(ushort4*)(Ob + ((size_t)(b * NTOK_ + n)) * FF_ + h * 64 + 16 * t + 4 * g) = uo;
    }
    asm volatile("" ::: "memory");
  }
}

// ---------------------------------------------------------------------------
// Kernel 3: output projection + bias + ReLU + skip -> pre (fp32, workspace).
// R4 form: 512 blocks, 32n x 64o tile, each wave one 16-o strip.
// ---------------------------------------------------------------------------
__global__ __launch_bounds__(256, 2) void proj_kernel(
    const unsigned short* __restrict__ Ob, const unsigned short* __restrict__ Wob,
    const float* __restrict__ bo, const float* __restrict__ x,
    float* __restrict__ pre) {
  __shared__ unsigned short Osh[32 * 72];
  __shared__ unsigned short Wsh[64 * 72];
  const int tid = threadIdx.x;
  const int lane = tid & 63, w = tid >> 6;
  const int lx = lane & 15, q = lane >> 4;
  const int n0 = blockIdx.x * 32;
  const int o0 = blockIdx.y * 64;
  const int b = blockIdx.z;

  const int srow = tid >> 3;
  const int soff = (tid & 7) * 8;
  const unsigned short* Og = Ob + ((size_t)(b * NTOK_ + n0 + srow)) * FF_ + soff;
  const unsigned short* Wg = Wob + (size_t)(o0 + srow) * FF_ + soff;

  for (int rep = 0; rep < PROJ_REP_; ++rep) {
    uint4 orr, wrr[2];
    orr = *(const uint4*)(Og);
#pragma unroll
    for (int r = 0; r < 2; ++r) wrr[r] = *(const uint4*)(Wg + (size_t)(32 * r) * FF_);

    f32x4 acc[2];
#pragma unroll
    for (int i = 0; i < 2; ++i) acc[i] = (f32x4){0.f, 0.f, 0.f, 0.f};

    for (int kk = 0; kk < 8; ++kk) {
      __syncthreads();
      *(uint4*)(Osh + srow * 72 + soff) = orr;
#pragma unroll
      for (int r = 0; r < 2; ++r)
        *(uint4*)(Wsh + (srow + 32 * r) * 72 + soff) = wrr[r];
      if (kk < 7) {
        const int c0 = (kk + 1) * 64;
        orr = *(const uint4*)(Og + c0);
#pragma unroll
        for (int r = 0; r < 2; ++r)
          wrr[r] = *(const uint4*)(Wg + (size_t)(32 * r) * FF_ + c0);
      }
      __syncthreads();
      short8 aF[2][2], bF[2];
#pragma unroll
      for (int i = 0; i < 2; ++i) {
        aF[i][0] = *(const short8*)(Osh + (16 * i + lx) * 72 + q * 8);
        aF[i][1] = *(const short8*)(Osh + (16 * i + lx) * 72 + 32 + q * 8);
      }
      bF[0] = *(const short8*)(Wsh + (16 * w + lx) * 72 + q * 8);
      bF[1] = *(const short8*)(Wsh + (16 * w + lx) * 72 + 32 + q * 8);
#pragma unroll
      for (int i = 0; i < 2; ++i) {
        acc[i] = __builtin_amdgcn_mfma_f32_16x16x32_bf16(aF[i][0], bF[0], acc[i], 0, 0, 0);
        acc[i] = __builtin_amdgcn_mfma_f32_16x16x32_bf16(aF[i][1], bF[1], acc[i], 0, 0, 0);
      }
    }

    const int o = o0 + 16 * w + lx;
    const float bias = bo[o];
#pragma unroll
    for (int i = 0; i < 2; ++i) {
      const int n = n0 + 16 * i + 4 * q;
      const float4 xv = *(const float4*)(x + ((size_t)(b * CIN_ + o)) * NTOK_ + n);
      float4 v;
      v.x = fmaxf(acc[i][0] + bias, 0.f) + xv.x;
      v.y = fmaxf(acc[i][1] + bias, 0.f) + xv.y;
      v.z = fmaxf(acc[i][2] + bias, 0.f) + xv.z;
      v.w = fmaxf(acc[i][3] + bias, 0.f) + xv.w;
      *(float4*)(pre + ((size_t)(b * COUT_ + o)) * NTOK_ + n) = v;
    }
    asm volatile("" ::: "memory");
  }
}

// ---------------------------------------------------------------------------
// Kernel 4: BatchNorm, OUT-OF-PLACE (pre -> out) so it is idempotent and can
// be rep-looped. 512 threads/block (R4 form). Same math as in-place version.
// ---------------------------------------------------------------------------
__global__ __launch_bounds__(512) void bn_kernel(
    const float* __restrict__ pre, float* __restrict__ out,
    const float* __restrict__ gamma, const float* __restrict__ beta) {
  __shared__ float red[16];
  const int c = blockIdx.x;
  const int tid = threadIdx.x;
  const int lane = tid & 63, w = tid >> 6;

  for (int rep = 0; rep < BN_REP_; ++rep) {
    float4 v[2];
    float s = 0.f, s2 = 0.f;
#pragma unroll
    for (int b = 0; b < BB_; ++b) {
      const float* base = pre + ((size_t)(b * COUT_ + c)) * NTOK_;
      const float4 t = *(const float4*)(base + 4 * tid);
      v[b] = t;
      s += t.x + t.y + t.z + t.w;
      s2 += t.x * t.x + t.y * t.y + t.z * t.z + t.w * t.w;
    }
#pragma unroll
    for (int off = 32; off >= 1; off >>= 1) {
      s += __shfl_xor(s, off);
      s2 += __shfl_xor(s2, off);
    }
    if (lane == 0) { red[w] = s; red[8 + w] = s2; }
    __syncthreads();
    float S = 0.f, S2 = 0.f;
#pragma unroll
    for (int i = 0; i < 8; ++i) { S += red[i]; S2 += red[8 + i]; }
    const float inv = 1.0f / (float)(BB_ * NTOK_);
    const float mean = S * inv;
    const float var = S2 * inv - mean * mean;
    const float sc = rsqrtf(var + BNEPS_) * gamma[c];
    const float bt = beta[c];
#pragma unroll
    for (int b = 0; b < BB_; ++b) {
      float* base = out + ((size_t)(b * COUT_ + c)) * NTOK_;
      float4 t = v[b];
      t.x = (t.x - mean) * sc + bt;
      t.y = (t.y - mean) * sc + bt;
      t.z = (t.z - mean) * sc + bt;
      t.w = (t.w - mean) * sc + bt;
      *(float4*)(base + 4 * tid) = t;
    }
    __syncthreads();                 // red[] reuse guard across reps
    asm volatile("" ::: "memory");
  }
}

extern "C" void kernel_launch(void* const* d_in, const int* in_sizes, int n_in,
                              void* d_out, int out_size, void* d_ws, size_t ws_size,
                              hipStream_t stream) {
  (void)in_sizes; (void)n_in; (void)out_size; (void)ws_size;
  const float* x = (const float*)d_in[0];
  const float* WK = (const float*)d_in[1];
  const float* WQ = (const float*)d_in[2];
  const float* WV = (const float*)d_in[3];
  const float* Wo = (const float*)d_in[4];
  const float* bo = (const float*)d_in[5];
  const float* gamma = (const float*)d_in[6];
  const float* beta = (const float*)d_in[7];

  char* ws = (char*)d_ws;
  unsigned short* xT  = (unsigned short*)(ws);                    // 2 MB
  unsigned short* Wkb = (unsigned short*)(ws + 2097152);          // 256 KB x4
  unsigned short* Wqb = (unsigned short*)(ws + 2359296);
  unsigned short* Wvb = (unsigned short*)(ws + 2621440);
  unsigned short* Wob = (unsigned short*)(ws + 2883584);
  unsigned short* Kb  = (unsigned short*)(ws + 3145728);          // 4 MB
  unsigned short* Qb  = (unsigned short*)(ws + 7340032);          // 4 MB
  unsigned short* Vt  = (unsigned short*)(ws + 11534336);         // 4 MB
  unsigned short* Ob  = (unsigned short*)(ws + 15728640);         // 4 MB
  float* pre          = (float*)(ws + 19922944);                  // 4 MB
  float* out = (float*)d_out;

  prep_kernel<<<384, 256, 0, stream>>>(x, WK, WQ, WV, Wo, xT, Wkb, Wqb, Wvb, Wob);
  qkv_kernel<<<dim3(32, 4, 6), 256, 0, stream>>>(xT, Wkb, Wqb, Wvb, Kb, Qb, Vt);
  attn_kernel<<<dim3(512, 1, 1), 256, 0, stream>>>(Kb, Qb, Vt, Ob);
  proj_kernel<<<dim3(64, 4, 2), 256, 0, stream>>>(Ob, Wob, bo, x, pre);
  bn_kernel<<<256, 512, 0, stream>>>(pre, out, gamma, beta);
}

// Round 8
// 137.276 us; speedup vs baseline: 3.6028x; 3.6028x over previous
//
#include <hip/hip_runtime.h>
#include <math.h>

#define BB_   2
#define CIN_  256
#define NTOK_ 2048
#define FF_   512
#define COUT_ 256
#define NH_   8
#define DH_   64
#define HW_   128
#define BNEPS_ 1e-5f
#define SCALE_LOG2_ 0.09016844005556021f  /* log2(e)/16, folded into K at qkv */

typedef __attribute__((ext_vector_type(8))) short short8;
typedef __attribute__((ext_vector_type(4))) short bfx4;
typedef __attribute__((ext_vector_type(4))) float f32x4;

#if __has_builtin(__builtin_amdgcn_mfma_f32_16x16x16_bf16)
#define MFMA16(a, b, c) __builtin_amdgcn_mfma_f32_16x16x16_bf16(a, b, c, 0, 0, 0)
#else
#define MFMA16(a, b, c) __builtin_amdgcn_mfma_f32_16x16x16bf16_1k(a, b, c, 0, 0, 0)
#endif

__device__ inline unsigned short f2bf(float f) {
  union { float f; unsigned u; } v; v.f = f;
  unsigned r = (v.u + 0x7FFF + ((v.u >> 16) & 1)) >> 16;  // RNE
  return (unsigned short)r;
}

// async global->LDS DMA, 16 B per lane; LDS dest = wave-uniform base + lane*16
__device__ __forceinline__ void dma16(const unsigned short* g, unsigned short* l) {
  __builtin_amdgcn_global_load_lds(
      (const __attribute__((address_space(1))) void*)g,
      (__attribute__((address_space(3))) void*)l, 16, 0, 0);
}

// ---------------------------------------------------------------------------
// Kernel 0: prep — x fp32 [b][c][n] -> xT bf16 [b][n][c]; weights -> bf16.
// ---------------------------------------------------------------------------
__global__ __launch_bounds__(256) void prep_kernel(
    const float* __restrict__ x, const float* __restrict__ WK,
    const float* __restrict__ WQ, const float* __restrict__ WV,
    const float* __restrict__ Wo, unsigned short* __restrict__ xT,
    unsigned short* __restrict__ Wkb, unsigned short* __restrict__ Wqb,
    unsigned short* __restrict__ Wvb, unsigned short* __restrict__ Wob) {
  __shared__ float T[64 * 65];
  const int tid = threadIdx.x;
  const int bid = blockIdx.x;
  if (bid < 256) {
    const int b = bid >> 7;
    const int rem = bid & 127;
    const int n0 = (rem >> 2) * 64;
    const int c0 = (rem & 3) * 64;
#pragma unroll
    for (int p = 0; p < 4; ++p) {
      const int idx = tid + 256 * p;
      const int row = idx >> 4, col = (idx & 15) * 4;
      const float4 v =
          *(const float4*)(x + (size_t)(b * CIN_ + c0 + row) * NTOK_ + n0 + col);
      T[row * 65 + col + 0] = v.x; T[row * 65 + col + 1] = v.y;
      T[row * 65 + col + 2] = v.z; T[row * 65 + col + 3] = v.w;
    }
    __syncthreads();
#pragma unroll
    for (int p = 0; p < 2; ++p) {
      const int idx = tid + 256 * p;
      const int nl = idx >> 3, c8 = (idx & 7) * 8;
      unsigned short u[8];
#pragma unroll
      for (int i = 0; i < 8; ++i) u[i] = f2bf(T[(c8 + i) * 65 + nl]);
      *(uint4*)(xT + ((size_t)(b * NTOK_ + n0 + nl)) * CIN_ + c0 + c8) =
          *(uint4*)u;
    }
  } else {
    const int t = bid - 256;
    const int which = t >> 5, blk = t & 31;
    const float* src = which == 0 ? WK : which == 1 ? WQ : which == 2 ? WV : Wo;
    unsigned short* dst = which == 0 ? Wkb : which == 1 ? Wqb : which == 2 ? Wvb : Wob;
    const int base = blk * 4096 + tid * 16;
#pragma unroll
    for (int p = 0; p < 4; ++p) {
      const float4 v = *(const float4*)(src + base + p * 4);
      ushort4 u;
      u.x = f2bf(v.x); u.y = f2bf(v.y); u.z = f2bf(v.z); u.w = f2bf(v.w);
      *(ushort4*)(dst + base + p * 4) = u;
    }
  }
}

// ---------------------------------------------------------------------------
// Kernel 1: QKV projection via MFMA. 128f x 64n tile, 768 blocks, 3 blocks/CU.
// R8: coalesced epilogue. R7 counters showed 36.6 MB/rep HBM writes vs 12 MB
// ideal (V^T stores = 8B/lane @ 4KB stride = 8x partial-line amplification;
// K/Q = 32B of 128B rows). Fix: after MFMA, stage the output tile in Wsh
// ([128][72] bf16, free after the K-loop), then stream out 16B/lane with each
// 128B output row written as one full line. Bit-identical values.
// ---------------------------------------------------------------------------
__global__ __launch_bounds__(256, 3) void qkv_kernel(
    const unsigned short* __restrict__ xT, const unsigned short* __restrict__ Wkb,
    const unsigned short* __restrict__ Wqb, const unsigned short* __restrict__ Wvb,
    unsigned short* __restrict__ Kb, unsigned short* __restrict__ Qb,
    unsigned short* __restrict__ Vt) {
  __shared__ unsigned short Wsh[128 * 72];
  __shared__ unsigned short Xsh[64 * 72];
  const int tid = threadIdx.x;
  const int lane = tid & 63, w = tid >> 6;
  const int lx = lane & 15, q = lane >> 4;
  const int wm = w >> 1, wn = w & 1;
  const int n0 = blockIdx.x * 64;
  const int f0 = blockIdx.y * 128;
  const int b = blockIdx.z / 3, which = blockIdx.z % 3;
  const unsigned short* Wb = which == 0 ? Wkb : which == 1 ? Wqb : Wvb;

  const int srow = tid >> 3;
  const int soff = (tid & 7) * 8;
  const unsigned short* Wg = Wb + (size_t)(f0 + srow) * CIN_ + soff;
  const unsigned short* Xg = xT + ((size_t)(b * NTOK_ + n0 + srow)) * CIN_ + soff;

  uint4 wr[4], xr[2];
#pragma unroll
  for (int r = 0; r < 4; ++r) wr[r] = *(const uint4*)(Wg + (size_t)(32 * r) * CIN_);
#pragma unroll
  for (int r = 0; r < 2; ++r) xr[r] = *(const uint4*)(Xg + (size_t)(32 * r) * CIN_);

  f32x4 acc[4][2];
#pragma unroll
  for (int i = 0; i < 4; ++i)
#pragma unroll
    for (int j = 0; j < 2; ++j) acc[i][j] = (f32x4){0.f, 0.f, 0.f, 0.f};

  for (int kk = 0; kk < 4; ++kk) {
    __syncthreads();
#pragma unroll
    for (int r = 0; r < 4; ++r) *(uint4*)(Wsh + (srow + 32 * r) * 72 + soff) = wr[r];
#pragma unroll
    for (int r = 0; r < 2; ++r) *(uint4*)(Xsh + (srow + 32 * r) * 72 + soff) = xr[r];
    if (kk < 3) {
      const int c0 = (kk + 1) * 64;
#pragma unroll
      for (int r = 0; r < 4; ++r) wr[r] = *(const uint4*)(Wg + (size_t)(32 * r) * CIN_ + c0);
#pragma unroll
      for (int r = 0; r < 2; ++r) xr[r] = *(const uint4*)(Xg + (size_t)(32 * r) * CIN_ + c0);
    }
    __syncthreads();
    short8 xF[2][2];
#pragma unroll
    for (int i = 0; i < 2; ++i) {
      xF[i][0] = *(const short8*)(Xsh + (32 * wn + 16 * i + lx) * 72 + q * 8);
      xF[i][1] = *(const short8*)(Xsh + (32 * wn + 16 * i + lx) * 72 + 32 + q * 8);
    }
    if (which < 2) {
#pragma unroll
      for (int i = 0; i < 4; ++i) {
        const short8 w0 = *(const short8*)(Wsh + (64 * wm + 16 * i + lx) * 72 + q * 8);
        const short8 w1 = *(const short8*)(Wsh + (64 * wm + 16 * i + lx) * 72 + 32 + q * 8);
#pragma unroll
        for (int j = 0; j < 2; ++j) {
          acc[i][j] = __builtin_amdgcn_mfma_f32_16x16x32_bf16(w0, xF[j][0], acc[i][j], 0, 0, 0);
          acc[i][j] = __builtin_amdgcn_mfma_f32_16x16x32_bf16(w1, xF[j][1], acc[i][j], 0, 0, 0);
        }
      }
    } else {
#pragma unroll
      for (int jf = 0; jf < 4; ++jf) {
        const short8 w0 = *(const short8*)(Wsh + (64 * wm + 16 * jf + lx) * 72 + q * 8);
        const short8 w1 = *(const short8*)(Wsh + (64 * wm + 16 * jf + lx) * 72 + 32 + q * 8);
#pragma unroll
        for (int i = 0; i < 2; ++i) {
          acc[jf][i] = __builtin_amdgcn_mfma_f32_16x16x32_bf16(xF[i][0], w0, acc[jf][i], 0, 0, 0);
          acc[jf][i] = __builtin_amdgcn_mfma_f32_16x16x32_bf16(xF[i][1], w1, acc[jf][i], 0, 0, 0);
        }
      }
    }
  }

  // ---- coalesced epilogue: stage output tile in Wsh, then full-line stores
  __syncthreads();   // all Wsh fragment reads complete before reuse

  if (which < 2) {
    // K/Q: row = wm*64 + (n offset 32wn+16j+lx), col = d0 = 16i+4q
    const float sc = (which == 0) ? SCALE_LOG2_ : 1.0f;
#pragma unroll
    for (int i = 0; i < 4; ++i)
#pragma unroll
      for (int j = 0; j < 2; ++j) {
        const int row = wm * 64 + 32 * wn + 16 * j + lx;
        const int d0 = 16 * i + 4 * q;
        ushort4 u;
        u.x = f2bf(acc[i][j][0] * sc); u.y = f2bf(acc[i][j][1] * sc);
        u.z = f2bf(acc[i][j][2] * sc); u.w = f2bf(acc[i][j][3] * sc);
        *(ushort4*)(Wsh + row * 72 + d0) = u;
      }
  } else {
    // V: row = wm*64 + (d offset 16jf+lx), col = n offset 32wn+16i+4q
#pragma unroll
    for (int jf = 0; jf < 4; ++jf)
#pragma unroll
      for (int i = 0; i < 2; ++i) {
        const int row = wm * 64 + 16 * jf + lx;
        const int nc = 32 * wn + 16 * i + 4 * q;
        ushort4 u;
        u.x = f2bf(acc[jf][i][0]); u.y = f2bf(acc[jf][i][1]);
        u.z = f2bf(acc[jf][i][2]); u.w = f2bf(acc[jf][i][3]);
        *(ushort4*)(Wsh + row * 72 + nc) = u;
      }
  }
  __syncthreads();

  const int h0 = f0 >> 6;
  if (which < 2) {
    unsigned short* Y = (which == 0 ? Kb : Qb);
#pragma unroll
    for (int p = 0; p < 4; ++p) {
      const int idx = tid + 256 * p;            // 0..1023
      const int row = idx >> 3;                 // 0..127: h' = row>>6, nn = row&63
      const int c = (idx & 7) * 8;              // 16B chunk within 128B row
      const uint4 val = *(const uint4*)(Wsh + row * 72 + c);
      *(uint4*)(Y + ((size_t)((b * NH_ + h0 + (row >> 6)) * NTOK_ + n0 + (row & 63))) * DH_ + c) = val;
    }
  } else {
#pragma unroll
    for (int p = 0; p < 4; ++p) {
      const int idx = tid + 256 * p;
      const int row = idx >> 3;                 // h' = row>>6, d = row&63
      const int c = (idx & 7) * 8;
      const uint4 val = *(const uint4*)(Wsh + row * 72 + c);
      *(uint4*)(Vt + ((size_t)((b * NH_ + h0 + (row >> 6)) * DH_ + (row & 63))) * NTOK_ + n0 + c) = val;
    }
  }
}

// ---------------------------------------------------------------------------
// Kernel 2: block-causal attention — S^T trick, DMA dbuf, XCD grouping, LPT.
// ---------------------------------------------------------------------------
__global__ __launch_bounds__(256, 2) void attn_kernel(
    const unsigned short* __restrict__ Kb, const unsigned short* __restrict__ Qb,
    const unsigned short* __restrict__ Vt, unsigned short* __restrict__ Ob) {
  __shared__ __align__(16) unsigned short Qbuf[2][8192];
  __shared__ __align__(16) unsigned short Vbuf[2][8192];

  const int tid = threadIdx.x;
  const int lane = tid & 63;
  const int w = tid >> 6;
  const int lx = lane & 15;
  const int g = lane >> 4;

  const int bid = blockIdx.x;
  const int xcd = bid & 7;
  const int k = bid >> 3;
  const int bh = xcd * 2 + (k & 1);
  const int u = k >> 1;
  const int iblk = (u < 16) ? (31 - u) : (u - 16);
  const int h = bh & 7, b = bh >> 3;
  const int i0 = iblk * 64;
  const int njt = (iblk >> 1) + 1;

  const size_t bhs = (size_t)b * NH_ + h;
  const unsigned short* Kg = Kb + bhs * (size_t)NTOK_ * DH_ + (size_t)i0 * DH_;
  const unsigned short* Qg = Qb + bhs * (size_t)NTOK_ * DH_;
  const unsigned short* Vg = Vt + bhs * (size_t)DH_ * NTOK_;

  auto stage = [&](int buf, int j0) {
#pragma unroll
    for (int cc = 0; cc < 4; ++cc) {
      const int chunk = 4 * w + cc;
      {  // Q
        const int row = chunk * 8 + (lane >> 3);
        const int grp = (lane & 7) ^ (row & 7);
        dma16(Qg + (size_t)(j0 + row) * DH_ + grp * 8, &Qbuf[buf][chunk * 512]);
      }
      {  // V
        const int row = chunk * 4 + (lane >> 4);
        const int grp = (lane & 15) ^ (row & 7);
        dma16(Vg + (size_t)row * NTOK_ + j0 + grp * 8, &Vbuf[buf][chunk * 512]);
      }
    }
  };

  const short8 aK0 = *(const short8*)(Kg + (16 * w + lx) * DH_ + g * 8);
  const short8 aK1 = *(const short8*)(Kg + (16 * w + lx) * DH_ + 32 + g * 8);

  f32x4 o[4];
#pragma unroll
  for (int t = 0; t < 4; ++t) o[t] = (f32x4){0.f, 0.f, 0.f, 0.f};
  float rs = 0.f;

  const int fr0 = ((g ^ (lx & 7)) << 3);
  const int fr1 = (((4 + g) ^ (lx & 7)) << 3);

  stage(0, 0);
  __syncthreads();

  int cur = 0;
  for (int jt = 0; jt < njt; ++jt) {
    if (jt + 1 < njt) stage(cur ^ 1, (jt + 1) * 128);

    const unsigned short* Qs = Qbuf[cur];
    const unsigned short* Vs = Vbuf[cur];

    f32x4 sa[8];
#pragma unroll
    for (int s = 0; s < 8; ++s) {
      const int row = 16 * s + lx;
      const short8 a0 = *(const short8*)(Qs + row * 64 + fr0);
      const short8 a1 = *(const short8*)(Qs + row * 64 + fr1);
      sa[s] = (f32x4){0.f, 0.f, 0.f, 0.f};
      sa[s] = __builtin_amdgcn_mfma_f32_16x16x32_bf16(a0, aK0, sa[s], 0, 0, 0);
      sa[s] = __builtin_amdgcn_mfma_f32_16x16x32_bf16(a1, aK1, sa[s], 0, 0, 0);
    }

#pragma unroll
    for (int s = 0; s < 8; ++s) {
      const float p0 = __builtin_amdgcn_exp2f(sa[s][0]);
      const float p1 = __builtin_amdgcn_exp2f(sa[s][1]);
      const float p2 = __builtin_amdgcn_exp2f(sa[s][2]);
      const float p3 = __builtin_amdgcn_exp2f(sa[s][3]);
      rs += (p0 + p1) + (p2 + p3);
      union { unsigned u[2]; bfx4 v; } pk;
      pk.u[0] = (__builtin_bit_cast(unsigned, p0) >> 16) |
                (__builtin_bit_cast(unsigned, p1) & 0xFFFF0000u);
      pk.u[1] = (__builtin_bit_cast(unsigned, p2) >> 16) |
                (__builtin_bit_cast(unsigned, p3) & 0xFFFF0000u);
      const int jgrp = 2 * s + (g >> 1);
      const int joff = (g & 1) << 2;
#pragma unroll
      for (int t = 0; t < 4; ++t) {
        const int row = 16 * t + lx;
        const bfx4 va = *(const bfx4*)(Vs + row * 128 +
                                       ((jgrp ^ (row & 7)) << 3) + joff);
        o[t] = MFMA16(va, pk.v, o[t]);
      }
    }

    __syncthreads();
    cur ^= 1;
  }

  rs += __shfl_xor(rs, 16);
  rs += __shfl_xor(rs, 32);
  const float invl = 1.0f / rs;
  const int n = i0 + 16 * w + lx;
#pragma unroll
  for (int t = 0; t < 4; ++t) {
    ushort4 uo;
    uo.x = f2bf(o[t][0] * invl); uo.y = f2bf(o[t][1] * invl);
    uo.z = f2bf(o[t][2] * invl); uo.w = f2bf(o[t][3] * invl);
    *(ushort4*)(Ob + ((size_t)(b * NTOK_ + n)) * FF_ + h * 64 + 16 * t + 4 * g) = uo;
  }
}

// ---------------------------------------------------------------------------
// Kernel 3: output projection + bias + ReLU + skip -> d_out fp32 (R4 form).
// ---------------------------------------------------------------------------
__global__ __launch_bounds__(256, 2) void proj_kernel(
    const unsigned short* __restrict__ Ob, const unsigned short* __restrict__ Wob,
    const float* __restrict__ bo, const float* __restrict__ x,
    float* __restrict__ pre) {
  __shared__ unsigned short Osh[32 * 72];
  __shared__ unsigned short Wsh[64 * 72];
  const int tid = threadIdx.x;
  const int lane = tid & 63, w = tid >> 6;
  const int lx = lane & 15, q = lane >> 4;
  const int n0 = blockIdx.x * 32;
  const int o0 = blockIdx.y * 64;
  const int b = blockIdx.z;

  const int srow = tid >> 3;
  const int soff = (tid & 7) * 8;
  const unsigned short* Og = Ob + ((size_t)(b * NTOK_ + n0 + srow)) * FF_ + soff;
  const unsigned short* Wg = Wob + (size_t)(o0 + srow) * FF_ + soff;

  uint4 orr, wrr[2];
  orr = *(const uint4*)(Og);
#pragma unroll
  for (int r = 0; r < 2; ++r) wrr[r] = *(const uint4*)(Wg + (size_t)(32 * r) * FF_);

  f32x4 acc[2];
#pragma unroll
  for (int i = 0; i < 2; ++i) acc[i] = (f32x4){0.f, 0.f, 0.f, 0.f};

  for (int kk = 0; kk < 8; ++kk) {
    __syncthreads();
    *(uint4*)(Osh + srow * 72 + soff) = orr;
#pragma unroll
    for (int r = 0; r < 2; ++r)
      *(uint4*)(Wsh + (srow + 32 * r) * 72 + soff) = wrr[r];
    if (kk < 7) {
      const int c0 = (kk + 1) * 64;
      orr = *(const uint4*)(Og + c0);
#pragma unroll
      for (int r = 0; r < 2; ++r)
        wrr[r] = *(const uint4*)(Wg + (size_t)(32 * r) * FF_ + c0);
    }
    __syncthreads();
    short8 aF[2][2], bF[2];
#pragma unroll
    for (int i = 0; i < 2; ++i) {
      aF[i][0] = *(const short8*)(Osh + (16 * i + lx) * 72 + q * 8);
      aF[i][1] = *(const short8*)(Osh + (16 * i + lx) * 72 + 32 + q * 8);
    }
    bF[0] = *(const short8*)(Wsh + (16 * w + lx) * 72 + q * 8);
    bF[1] = *(const short8*)(Wsh + (16 * w + lx) * 72 + 32 + q * 8);
#pragma unroll
    for (int i = 0; i < 2; ++i) {
      acc[i] = __builtin_amdgcn_mfma_f32_16x16x32_bf16(aF[i][0], bF[0], acc[i], 0, 0, 0);
      acc[i] = __builtin_amdgcn_mfma_f32_16x16x32_bf16(aF[i][1], bF[1], acc[i], 0, 0, 0);
    }
  }

  const int o = o0 + 16 * w + lx;
  const float bias = bo[o];
#pragma unroll
  for (int i = 0; i < 2; ++i) {
    const int n = n0 + 16 * i + 4 * q;
    const float4 xv = *(const float4*)(x + ((size_t)(b * CIN_ + o)) * NTOK_ + n);
    float4 v;
    v.x = fmaxf(acc[i][0] + bias, 0.f) + xv.x;
    v.y = fmaxf(acc[i][1] + bias, 0.f) + xv.y;
    v.z = fmaxf(acc[i][2] + bias, 0.f) + xv.z;
    v.w = fmaxf(acc[i][3] + bias, 0.f) + xv.w;
    *(float4*)(pre + ((size_t)(b * COUT_ + o)) * NTOK_ + n) = v;
  }
}

// ---------------------------------------------------------------------------
// Kernel 4: BatchNorm in place, 512 threads/block (R4 form).
// ---------------------------------------------------------------------------
__global__ __launch_bounds__(512) void bn_kernel(
    float* __restrict__ out, const float* __restrict__ gamma,
    const float* __restrict__ beta) {
  __shared__ float red[16];
  const int c = blockIdx.x;
  const int tid = threadIdx.x;
  const int lane = tid & 63, w = tid >> 6;

  float4 v[2];
  float s = 0.f, s2 = 0.f;
#pragma unroll
  for (int b = 0; b < BB_; ++b) {
    float* base = out + ((size_t)(b * COUT_ + c)) * NTOK_;
    const float4 t = *(const float4*)(base + 4 * tid);
    v[b] = t;
    s += t.x + t.y + t.z + t.w;
    s2 += t.x * t.x + t.y * t.y + t.z * t.z + t.w * t.w;
  }
#pragma unroll
  for (int off = 32; off >= 1; off >>= 1) {
    s += __shfl_xor(s, off);
    s2 += __shfl_xor(s2, off);
  }
  if (lane == 0) { red[w] = s; red[8 + w] = s2; }
  __syncthreads();
  float S = 0.f, S2 = 0.f;
#pragma unroll
  for (int i = 0; i < 8; ++i) { S += red[i]; S2 += red[8 + i]; }
  const float inv = 1.0f / (float)(BB_ * NTOK_);
  const float mean = S * inv;
  const float var = S2 * inv - mean * mean;
  const float sc = rsqrtf(var + BNEPS_) * gamma[c];
  const float bt = beta[c];
#pragma unroll
  for (int b = 0; b < BB_; ++b) {
    float* base = out + ((size_t)(b * COUT_ + c)) * NTOK_;
    float4 t = v[b];
    t.x = (t.x - mean) * sc + bt;
    t.y = (t.y - mean) * sc + bt;
    t.z = (t.z - mean) * sc + bt;
    t.w = (t.w - mean) * sc + bt;
    *(float4*)(base + 4 * tid) = t;
  }
}

extern "C" void kernel_launch(void* const* d_in, const int* in_sizes, int n_in,
                              void* d_out, int out_size, void* d_ws, size_t ws_size,
                              hipStream_t stream) {
  (void)in_sizes; (void)n_in; (void)out_size; (void)ws_size;
  const float* x = (const float*)d_in[0];
  const float* WK = (const float*)d_in[1];
  const float* WQ = (const float*)d_in[2];
  const float* WV = (const float*)d_in[3];
  const float* Wo = (const float*)d_in[4];
  const float* bo = (const float*)d_in[5];
  const float* gamma = (const float*)d_in[6];
  const float* beta = (const float*)d_in[7];

  char* ws = (char*)d_ws;
  unsigned short* xT  = (unsigned short*)(ws);                    // 2 MB
  unsigned short* Wkb = (unsigned short*)(ws + 2097152);          // 256 KB x4
  unsigned short* Wqb = (unsigned short*)(ws + 2359296);
  unsigned short* Wvb = (unsigned short*)(ws + 2621440);
  unsigned short* Wob = (unsigned short*)(ws + 2883584);
  unsigned short* Kb  = (unsigned short*)(ws + 3145728);          // 4 MB
  unsigned short* Qb  = (unsigned short*)(ws + 7340032);          // 4 MB
  unsigned short* Vt  = (unsigned short*)(ws + 11534336);         // 4 MB
  unsigned short* Ob  = (unsigned short*)(ws + 15728640);         // 4 MB
  float* out = (float*)d_out;

  prep_kernel<<<384, 256, 0, stream>>>(x, WK, WQ, WV, Wo, xT, Wkb, Wqb, Wvb, Wob);
  qkv_kernel<<<dim3(32, 4, 6), 256, 0, stream>>>(xT, Wkb, Wqb, Wvb, Kb, Qb, Vt);
  attn_kernel<<<dim3(512, 1, 1), 256, 0, stream>>>(Kb, Qb, Vt, Ob);
  proj_kernel<<<dim3(64, 4, 2), 256, 0, stream>>>(Ob, Wob, bo, x, out);
  bn_kernel<<<256, 512, 0, stream>>>(out, gamma, beta);
}

// Round 9
// 119.342 us; speedup vs baseline: 4.1442x; 1.1503x over previous
//
#include <hip/hip_runtime.h>
#include <math.h>

#define BB_   2
#define CIN_  256
#define NTOK_ 2048
#define FF_   512
#define COUT_ 256
#define NH_   8
#define DH_   64
#define HW_   128
#define BNEPS_ 1e-5f
#define SCALE_LOG2_ 0.09016844005556021f  /* log2(e)/16, folded into K at qkv */

typedef __attribute__((ext_vector_type(8))) short short8;
typedef __attribute__((ext_vector_type(4))) short bfx4;
typedef __attribute__((ext_vector_type(4))) float f32x4;

#if __has_builtin(__builtin_amdgcn_mfma_f32_16x16x16_bf16)
#define MFMA16(a, b, c) __builtin_amdgcn_mfma_f32_16x16x16_bf16(a, b, c, 0, 0, 0)
#else
#define MFMA16(a, b, c) __builtin_amdgcn_mfma_f32_16x16x16bf16_1k(a, b, c, 0, 0, 0)
#endif

__device__ inline unsigned short f2bf(float f) {
  union { float f; unsigned u; } v; v.f = f;
  unsigned r = (v.u + 0x7FFF + ((v.u >> 16) & 1)) >> 16;  // RNE
  return (unsigned short)r;
}

// async global->LDS DMA, 16 B per lane; LDS dest = wave-uniform base + lane*16
__device__ __forceinline__ void dma16(const unsigned short* g, unsigned short* l) {
  __builtin_amdgcn_global_load_lds(
      (const __attribute__((address_space(1))) void*)g,
      (__attribute__((address_space(3))) void*)l, 16, 0, 0);
}

// ---------------------------------------------------------------------------
// Kernel 1 (R9: prep fused away): QKV projection reading x/W fp32 DIRECTLY.
// Per K-step: stage x 64c x 64n fp32 tile into T[64][65] (prep's conflict-free
// pattern), convert columns -> Xsh bf16 rows with the SAME f2bf RNE as the old
// prep (bit-identical bf16); W staged fp32 -> bf16 in the same way. Costs one
// extra barrier per K-step; saves the prep dispatch + xT HBM round-trip.
// LDS 44.2 KB -> still 3 blocks/CU. R8 coalesced epilogue retained.
// ---------------------------------------------------------------------------
__global__ __launch_bounds__(256, 3) void qkv_kernel(
    const float* __restrict__ x, const float* __restrict__ WK,
    const float* __restrict__ WQ, const float* __restrict__ WV,
    unsigned short* __restrict__ Kb, unsigned short* __restrict__ Qb,
    unsigned short* __restrict__ Vt) {
  __shared__ unsigned short Wsh[128 * 72];
  __shared__ unsigned short Xsh[64 * 72];
  __shared__ float T[64 * 65];
  const int tid = threadIdx.x;
  const int lane = tid & 63, w = tid >> 6;
  const int lx = lane & 15, q = lane >> 4;
  const int wm = w >> 1, wn = w & 1;
  const int n0 = blockIdx.x * 64;
  const int f0 = blockIdx.y * 128;
  const int b = blockIdx.z / 3, which = blockIdx.z % 3;
  const float* Wb = which == 0 ? WK : which == 1 ? WQ : WV;

  const int srow = tid >> 3;          // 0..31
  const int soff = (tid & 7) * 8;     // 0..56
  const float* Wg = Wb + (size_t)(f0 + srow) * CIN_ + soff;
  // x fp32 tile loads: part p covers rows (tid>>4)+16p, cols 4*(tid&15)
  const int tc = tid >> 4;            // 0..15
  const int tn = (tid & 15) * 4;

  // prefetch K-step 0: W fp32 (4 row-chunks x 8 floats), x fp32 (4 float4)
  float4 wr[4][2], xr[4];
#pragma unroll
  for (int r = 0; r < 4; ++r) {
    wr[r][0] = *(const float4*)(Wg + (size_t)(32 * r) * CIN_);
    wr[r][1] = *(const float4*)(Wg + (size_t)(32 * r) * CIN_ + 4);
  }
#pragma unroll
  for (int p = 0; p < 4; ++p)
    xr[p] = *(const float4*)(x + (size_t)(b * CIN_ + tc + 16 * p) * NTOK_ + n0 + tn);

  f32x4 acc[4][2];
#pragma unroll
  for (int i = 0; i < 4; ++i)
#pragma unroll
    for (int j = 0; j < 2; ++j) acc[i][j] = (f32x4){0.f, 0.f, 0.f, 0.f};

  for (int kk = 0; kk < 4; ++kk) {
    __syncthreads();   // (A) previous MFMA reads done; T/Wsh writable
    // stage T fp32 (scalar stores, prep's pattern) + Wsh bf16 (converted)
#pragma unroll
    for (int p = 0; p < 4; ++p) {
      const int row = tc + 16 * p;
      T[row * 65 + tn + 0] = xr[p].x; T[row * 65 + tn + 1] = xr[p].y;
      T[row * 65 + tn + 2] = xr[p].z; T[row * 65 + tn + 3] = xr[p].w;
    }
#pragma unroll
    for (int r = 0; r < 4; ++r) {
      unsigned short u[8];
      u[0] = f2bf(wr[r][0].x); u[1] = f2bf(wr[r][0].y);
      u[2] = f2bf(wr[r][0].z); u[3] = f2bf(wr[r][0].w);
      u[4] = f2bf(wr[r][1].x); u[5] = f2bf(wr[r][1].y);
      u[6] = f2bf(wr[r][1].z); u[7] = f2bf(wr[r][1].w);
      *(uint4*)(Wsh + (srow + 32 * r) * 72 + soff) = *(uint4*)u;
    }
    __syncthreads();   // (B) T ready
    // convert T columns -> Xsh rows (bit-identical to prep's xT)
#pragma unroll
    for (int p = 0; p < 2; ++p) {
      const int idx = tid + 256 * p;
      const int nl = idx >> 3, c8 = (idx & 7) * 8;
      unsigned short u[8];
#pragma unroll
      for (int i = 0; i < 8; ++i) u[i] = f2bf(T[(c8 + i) * 65 + nl]);
      *(uint4*)(Xsh + nl * 72 + c8) = *(uint4*)u;
    }
    if (kk < 3) {      // prefetch next K-step fp32
      const int c0 = (kk + 1) * 64;
#pragma unroll
      for (int r = 0; r < 4; ++r) {
        wr[r][0] = *(const float4*)(Wg + (size_t)(32 * r) * CIN_ + c0);
        wr[r][1] = *(const float4*)(Wg + (size_t)(32 * r) * CIN_ + c0 + 4);
      }
#pragma unroll
      for (int p = 0; p < 4; ++p)
        xr[p] = *(const float4*)(x + (size_t)(b * CIN_ + c0 + tc + 16 * p) * NTOK_ + n0 + tn);
    }
    __syncthreads();   // (C) Xsh/Wsh ready
    short8 xF[2][2];
#pragma unroll
    for (int i = 0; i < 2; ++i) {
      xF[i][0] = *(const short8*)(Xsh + (32 * wn + 16 * i + lx) * 72 + q * 8);
      xF[i][1] = *(const short8*)(Xsh + (32 * wn + 16 * i + lx) * 72 + 32 + q * 8);
    }
    if (which < 2) {
#pragma unroll
      for (int i = 0; i < 4; ++i) {
        const short8 w0 = *(const short8*)(Wsh + (64 * wm + 16 * i + lx) * 72 + q * 8);
        const short8 w1 = *(const short8*)(Wsh + (64 * wm + 16 * i + lx) * 72 + 32 + q * 8);
#pragma unroll
        for (int j = 0; j < 2; ++j) {
          acc[i][j] = __builtin_amdgcn_mfma_f32_16x16x32_bf16(w0, xF[j][0], acc[i][j], 0, 0, 0);
          acc[i][j] = __builtin_amdgcn_mfma_f32_16x16x32_bf16(w1, xF[j][1], acc[i][j], 0, 0, 0);
        }
      }
    } else {
#pragma unroll
      for (int jf = 0; jf < 4; ++jf) {
        const short8 w0 = *(const short8*)(Wsh + (64 * wm + 16 * jf + lx) * 72 + q * 8);
        const short8 w1 = *(const short8*)(Wsh + (64 * wm + 16 * jf + lx) * 72 + 32 + q * 8);
#pragma unroll
        for (int i = 0; i < 2; ++i) {
          acc[jf][i] = __builtin_amdgcn_mfma_f32_16x16x32_bf16(xF[i][0], w0, acc[jf][i], 0, 0, 0);
          acc[jf][i] = __builtin_amdgcn_mfma_f32_16x16x32_bf16(xF[i][1], w1, acc[jf][i], 0, 0, 0);
        }
      }
    }
  }

  // ---- coalesced epilogue (R8): stage output tile in Wsh, full-line stores
  __syncthreads();

  if (which < 2) {
    const float sc = (which == 0) ? SCALE_LOG2_ : 1.0f;
#pragma unroll
    for (int i = 0; i < 4; ++i)
#pragma unroll
      for (int j = 0; j < 2; ++j) {
        const int row = wm * 64 + 32 * wn + 16 * j + lx;
        const int d0 = 16 * i + 4 * q;
        ushort4 u;
        u.x = f2bf(acc[i][j][0] * sc); u.y = f2bf(acc[i][j][1] * sc);
        u.z = f2bf(acc[i][j][2] * sc); u.w = f2bf(acc[i][j][3] * sc);
        *(ushort4*)(Wsh + row * 72 + d0) = u;
      }
  } else {
#pragma unroll
    for (int jf = 0; jf < 4; ++jf)
#pragma unroll
      for (int i = 0; i < 2; ++i) {
        const int row = wm * 64 + 16 * jf + lx;
        const int nc = 32 * wn + 16 * i + 4 * q;
        ushort4 u;
        u.x = f2bf(acc[jf][i][0]); u.y = f2bf(acc[jf][i][1]);
        u.z = f2bf(acc[jf][i][2]); u.w = f2bf(acc[jf][i][3]);
        *(ushort4*)(Wsh + row * 72 + nc) = u;
      }
  }
  __syncthreads();

  const int h0 = f0 >> 6;
  if (which < 2) {
    unsigned short* Y = (which == 0 ? Kb : Qb);
#pragma unroll
    for (int p = 0; p < 4; ++p) {
      const int idx = tid + 256 * p;
      const int row = idx >> 3;
      const int c = (idx & 7) * 8;
      const uint4 val = *(const uint4*)(Wsh + row * 72 + c);
      *(uint4*)(Y + ((size_t)((b * NH_ + h0 + (row >> 6)) * NTOK_ + n0 + (row & 63))) * DH_ + c) = val;
    }
  } else {
#pragma unroll
    for (int p = 0; p < 4; ++p) {
      const int idx = tid + 256 * p;
      const int row = idx >> 3;
      const int c = (idx & 7) * 8;
      const uint4 val = *(const uint4*)(Wsh + row * 72 + c);
      *(uint4*)(Vt + ((size_t)((b * NH_ + h0 + (row >> 6)) * DH_ + (row & 63))) * NTOK_ + n0 + c) = val;
    }
  }
}

// ---------------------------------------------------------------------------
// Kernel 2: block-causal attention — S^T trick, DMA dbuf, XCD grouping, LPT.
// ---------------------------------------------------------------------------
__global__ __launch_bounds__(256, 2) void attn_kernel(
    const unsigned short* __restrict__ Kb, const unsigned short* __restrict__ Qb,
    const unsigned short* __restrict__ Vt, unsigned short* __restrict__ Ob) {
  __shared__ __align__(16) unsigned short Qbuf[2][8192];
  __shared__ __align__(16) unsigned short Vbuf[2][8192];

  const int tid = threadIdx.x;
  const int lane = tid & 63;
  const int w = tid >> 6;
  const int lx = lane & 15;
  const int g = lane >> 4;

  const int bid = blockIdx.x;
  const int xcd = bid & 7;
  const int k = bid >> 3;
  const int bh = xcd * 2 + (k & 1);
  const int u = k >> 1;
  const int iblk = (u < 16) ? (31 - u) : (u - 16);
  const int h = bh & 7, b = bh >> 3;
  const int i0 = iblk * 64;
  const int njt = (iblk >> 1) + 1;

  const size_t bhs = (size_t)b * NH_ + h;
  const unsigned short* Kg = Kb + bhs * (size_t)NTOK_ * DH_ + (size_t)i0 * DH_;
  const unsigned short* Qg = Qb + bhs * (size_t)NTOK_ * DH_;
  const unsigned short* Vg = Vt + bhs * (size_t)DH_ * NTOK_;

  auto stage = [&](int buf, int j0) {
#pragma unroll
    for (int cc = 0; cc < 4; ++cc) {
      const int chunk = 4 * w + cc;
      {  // Q
        const int row = chunk * 8 + (lane >> 3);
        const int grp = (lane & 7) ^ (row & 7);
        dma16(Qg + (size_t)(j0 + row) * DH_ + grp * 8, &Qbuf[buf][chunk * 512]);
      }
      {  // V
        const int row = chunk * 4 + (lane >> 4);
        const int grp = (lane & 15) ^ (row & 7);
        dma16(Vg + (size_t)row * NTOK_ + j0 + grp * 8, &Vbuf[buf][chunk * 512]);
      }
    }
  };

  const short8 aK0 = *(const short8*)(Kg + (16 * w + lx) * DH_ + g * 8);
  const short8 aK1 = *(const short8*)(Kg + (16 * w + lx) * DH_ + 32 + g * 8);

  f32x4 o[4];
#pragma unroll
  for (int t = 0; t < 4; ++t) o[t] = (f32x4){0.f, 0.f, 0.f, 0.f};
  float rs = 0.f;

  const int fr0 = ((g ^ (lx & 7)) << 3);
  const int fr1 = (((4 + g) ^ (lx & 7)) << 3);

  stage(0, 0);
  __syncthreads();

  int cur = 0;
  for (int jt = 0; jt < njt; ++jt) {
    if (jt + 1 < njt) stage(cur ^ 1, (jt + 1) * 128);

    const unsigned short* Qs = Qbuf[cur];
    const unsigned short* Vs = Vbuf[cur];

    f32x4 sa[8];
#pragma unroll
    for (int s = 0; s < 8; ++s) {
      const int row = 16 * s + lx;
      const short8 a0 = *(const short8*)(Qs + row * 64 + fr0);
      const short8 a1 = *(const short8*)(Qs + row * 64 + fr1);
      sa[s] = (f32x4){0.f, 0.f, 0.f, 0.f};
      sa[s] = __builtin_amdgcn_mfma_f32_16x16x32_bf16(a0, aK0, sa[s], 0, 0, 0);
      sa[s] = __builtin_amdgcn_mfma_f32_16x16x32_bf16(a1, aK1, sa[s], 0, 0, 0);
    }

#pragma unroll
    for (int s = 0; s < 8; ++s) {
      const float p0 = __builtin_amdgcn_exp2f(sa[s][0]);
      const float p1 = __builtin_amdgcn_exp2f(sa[s][1]);
      const float p2 = __builtin_amdgcn_exp2f(sa[s][2]);
      const float p3 = __builtin_amdgcn_exp2f(sa[s][3]);
      rs += (p0 + p1) + (p2 + p3);
      union { unsigned u[2]; bfx4 v; } pk;
      pk.u[0] = (__builtin_bit_cast(unsigned, p0) >> 16) |
                (__builtin_bit_cast(unsigned, p1) & 0xFFFF0000u);
      pk.u[1] = (__builtin_bit_cast(unsigned, p2) >> 16) |
                (__builtin_bit_cast(unsigned, p3) & 0xFFFF0000u);
      const int jgrp = 2 * s + (g >> 1);
      const int joff = (g & 1) << 2;
#pragma unroll
      for (int t = 0; t < 4; ++t) {
        const int row = 16 * t + lx;
        const bfx4 va = *(const bfx4*)(Vs + row * 128 +
                                       ((jgrp ^ (row & 7)) << 3) + joff);
        o[t] = MFMA16(va, pk.v, o[t]);
      }
    }

    __syncthreads();
    cur ^= 1;
  }

  rs += __shfl_xor(rs, 16);
  rs += __shfl_xor(rs, 32);
  const float invl = 1.0f / rs;
  const int n = i0 + 16 * w + lx;
#pragma unroll
  for (int t = 0; t < 4; ++t) {
    ushort4 uo;
    uo.x = f2bf(o[t][0] * invl); uo.y = f2bf(o[t][1] * invl);
    uo.z = f2bf(o[t][2] * invl); uo.w = f2bf(o[t][3] * invl);
    *(ushort4*)(Ob + ((size_t)(b * NTOK_ + n)) * FF_ + h * 64 + 16 * t + 4 * g) = uo;
  }
}

// ---------------------------------------------------------------------------
// Kernel 3: output projection + bias + ReLU + skip -> d_out fp32 (R4 form).
// R9: stages Wo from fp32 with in-staging f2bf (bit-identical to old Wob).
// ---------------------------------------------------------------------------
__global__ __launch_bounds__(256, 2) void proj_kernel(
    const unsigned short* __restrict__ Ob, const float* __restrict__ Wo,
    const float* __restrict__ bo, const float* __restrict__ x,
    float* __restrict__ pre) {
  __shared__ unsigned short Osh[32 * 72];
  __shared__ unsigned short Wsh[64 * 72];
  const int tid = threadIdx.x;
  const int lane = tid & 63, w = tid >> 6;
  const int lx = lane & 15, q = lane >> 4;
  const int n0 = blockIdx.x * 32;
  const int o0 = blockIdx.y * 64;
  const int b = blockIdx.z;

  const int srow = tid >> 3;
  const int soff = (tid & 7) * 8;
  const unsigned short* Og = Ob + ((size_t)(b * NTOK_ + n0 + srow)) * FF_ + soff;
  const float* Wg = Wo + (size_t)(o0 + srow) * FF_ + soff;

  uint4 orr;
  float4 wrr[2][2];
  orr = *(const uint4*)(Og);
#pragma unroll
  for (int r = 0; r < 2; ++r) {
    wrr[r][0] = *(const float4*)(Wg + (size_t)(32 * r) * FF_);
    wrr[r][1] = *(const float4*)(Wg + (size_t)(32 * r) * FF_ + 4);
  }

  f32x4 acc[2];
#pragma unroll
  for (int i = 0; i < 2; ++i) acc[i] = (f32x4){0.f, 0.f, 0.f, 0.f};

  for (int kk = 0; kk < 8; ++kk) {
    __syncthreads();
    *(uint4*)(Osh + srow * 72 + soff) = orr;
#pragma unroll
    for (int r = 0; r < 2; ++r) {
      unsigned short u[8];
      u[0] = f2bf(wrr[r][0].x); u[1] = f2bf(wrr[r][0].y);
      u[2] = f2bf(wrr[r][0].z); u[3] = f2bf(wrr[r][0].w);
      u[4] = f2bf(wrr[r][1].x); u[5] = f2bf(wrr[r][1].y);
      u[6] = f2bf(wrr[r][1].z); u[7] = f2bf(wrr[r][1].w);
      *(uint4*)(Wsh + (srow + 32 * r) * 72 + soff) = *(uint4*)u;
    }
    if (kk < 7) {
      const int c0 = (kk + 1) * 64;
      orr = *(const uint4*)(Og + c0);
#pragma unroll
      for (int r = 0; r < 2; ++r) {
        wrr[r][0] = *(const float4*)(Wg + (size_t)(32 * r) * FF_ + c0);
        wrr[r][1] = *(const float4*)(Wg + (size_t)(32 * r) * FF_ + c0 + 4);
      }
    }
    __syncthreads();
    short8 aF[2][2], bF[2];
#pragma unroll
    for (int i = 0; i < 2; ++i) {
      aF[i][0] = *(const short8*)(Osh + (16 * i + lx) * 72 + q * 8);
      aF[i][1] = *(const short8*)(Osh + (16 * i + lx) * 72 + 32 + q * 8);
    }
    bF[0] = *(const short8*)(Wsh + (16 * w + lx) * 72 + q * 8);
    bF[1] = *(const short8*)(Wsh + (16 * w + lx) * 72 + 32 + q * 8);
#pragma unroll
    for (int i = 0; i < 2; ++i) {
      acc[i] = __builtin_amdgcn_mfma_f32_16x16x32_bf16(aF[i][0], bF[0], acc[i], 0, 0, 0);
      acc[i] = __builtin_amdgcn_mfma_f32_16x16x32_bf16(aF[i][1], bF[1], acc[i], 0, 0, 0);
    }
  }

  const int o = o0 + 16 * w + lx;
  const float bias = bo[o];
#pragma unroll
  for (int i = 0; i < 2; ++i) {
    const int n = n0 + 16 * i + 4 * q;
    const float4 xv = *(const float4*)(x + ((size_t)(b * CIN_ + o)) * NTOK_ + n);
    float4 v;
    v.x = fmaxf(acc[i][0] + bias, 0.f) + xv.x;
    v.y = fmaxf(acc[i][1] + bias, 0.f) + xv.y;
    v.z = fmaxf(acc[i][2] + bias, 0.f) + xv.z;
    v.w = fmaxf(acc[i][3] + bias, 0.f) + xv.w;
    *(float4*)(pre + ((size_t)(b * COUT_ + o)) * NTOK_ + n) = v;
  }
}

// ---------------------------------------------------------------------------
// Kernel 4: BatchNorm in place, 512 threads/block (R4 form).
// ---------------------------------------------------------------------------
__global__ __launch_bounds__(512) void bn_kernel(
    float* __restrict__ out, const float* __restrict__ gamma,
    const float* __restrict__ beta) {
  __shared__ float red[16];
  const int c = blockIdx.x;
  const int tid = threadIdx.x;
  const int lane = tid & 63, w = tid >> 6;

  float4 v[2];
  float s = 0.f, s2 = 0.f;
#pragma unroll
  for (int b = 0; b < BB_; ++b) {
    float* base = out + ((size_t)(b * COUT_ + c)) * NTOK_;
    const float4 t = *(const float4*)(base + 4 * tid);
    v[b] = t;
    s += t.x + t.y + t.z + t.w;
    s2 += t.x * t.x + t.y * t.y + t.z * t.z + t.w * t.w;
  }
#pragma unroll
  for (int off = 32; off >= 1; off >>= 1) {
    s += __shfl_xor(s, off);
    s2 += __shfl_xor(s2, off);
  }
  if (lane == 0) { red[w] = s; red[8 + w] = s2; }
  __syncthreads();
  float S = 0.f, S2 = 0.f;
#pragma unroll
  for (int i = 0; i < 8; ++i) { S += red[i]; S2 += red[8 + i]; }
  const float inv = 1.0f / (float)(BB_ * NTOK_);
  const float mean = S * inv;
  const float var = S2 * inv - mean * mean;
  const float sc = rsqrtf(var + BNEPS_) * gamma[c];
  const float bt = beta[c];
#pragma unroll
  for (int b = 0; b < BB_; ++b) {
    float* base = out + ((size_t)(b * COUT_ + c)) * NTOK_;
    float4 t = v[b];
    t.x = (t.x - mean) * sc + bt;
    t.y = (t.y - mean) * sc + bt;
    t.z = (t.z - mean) * sc + bt;
    t.w = (t.w - mean) * sc + bt;
    *(float4*)(base + 4 * tid) = t;
  }
}

extern "C" void kernel_launch(void* const* d_in, const int* in_sizes, int n_in,
                              void* d_out, int out_size, void* d_ws, size_t ws_size,
                              hipStream_t stream) {
  (void)in_sizes; (void)n_in; (void)out_size; (void)ws_size;
  const float* x = (const float*)d_in[0];
  const float* WK = (const float*)d_in[1];
  const float* WQ = (const float*)d_in[2];
  const float* WV = (const float*)d_in[3];
  const float* Wo = (const float*)d_in[4];
  const float* bo = (const float*)d_in[5];
  const float* gamma = (const float*)d_in[6];
  const float* beta = (const float*)d_in[7];

  char* ws = (char*)d_ws;
  unsigned short* Kb  = (unsigned short*)(ws + 3145728);          // 4 MB
  unsigned short* Qb  = (unsigned short*)(ws + 7340032);          // 4 MB
  unsigned short* Vt  = (unsigned short*)(ws + 11534336);         // 4 MB
  unsigned short* Ob  = (unsigned short*)(ws + 15728640);         // 4 MB
  float* out = (float*)d_out;

  qkv_kernel<<<dim3(32, 4, 6), 256, 0, stream>>>(x, WK, WQ, WV, Kb, Qb, Vt);
  attn_kernel<<<dim3(512, 1, 1), 256, 0, stream>>>(Kb, Qb, Vt, Ob);
  proj_kernel<<<dim3(64, 4, 2), 256, 0, stream>>>(Ob, Wo, bo, x, out);
  bn_kernel<<<256, 512, 0, stream>>>(out, gamma, beta);
}